// Round 15
// baseline (401.849 us; speedup 1.0000x reference)
//
#include <hip/hip_runtime.h>
#include <hip/hip_bf16.h>

#define Bn 32
#define Ln 1024
#define En 512
#define On 512

typedef __attribute__((ext_vector_type(8))) short bf16x8;
typedef __attribute__((ext_vector_type(4))) float f32x4;

__device__ __forceinline__ ushort f2bf(float x) {
    __hip_bfloat16 h = __float2bfloat16(x);
    return *reinterpret_cast<ushort*>(&h);
}
__device__ __forceinline__ float bf2f(ushort u) {
    __hip_bfloat16 h;
    *reinterpret_cast<ushort*>(&h) = u;
    return __bfloat162float(h);
}

__device__ __forceinline__ f32x4 mfma_bf16(bf16x8 a, bf16x8 b, f32x4 c) {
    return __builtin_amdgcn_mfma_f32_16x16x32_bf16(a, b, c, 0, 0, 0);
}

// ---------------------------------------------------------------------------
// Stage a 128x32 bf16 tile into linear LDS [128][32] via global_load_lds.
// (256-thread kernels)
// ---------------------------------------------------------------------------
__device__ __forceinline__ void stage(ushort* dst, const ushort* src, size_t rstride) {
    const int tid = threadIdx.x;
#pragma unroll
    for (int cc = 0; cc < 2; ++cc) {
        const int c = tid + cc * 256;
        const ushort* g = src + (size_t)(c >> 2) * rstride + (c & 3) * 8;
        ushort* l = dst + ((size_t)(tid >> 6) * 64 + cc * 256) * 8;
        __builtin_amdgcn_global_load_lds(
            (const __attribute__((address_space(1))) unsigned int*)g,
            (__attribute__((address_space(3))) unsigned int*)l, 16, 0, 0);
    }
}

// ---------------------------------------------------------------------------
// Pipelined NT bf16 GEMM core (round-6 proven): 128x128 tile, BK=32, 256
// threads, double-buffered LDS + counted vmcnt + raw barriers.
// ---------------------------------------------------------------------------
template <bool SPLIT>
__device__ __forceinline__ void nt_core_pipe(const ushort* __restrict__ Ah,
                                             const ushort* __restrict__ Al,
                                             const ushort* __restrict__ Bh,
                                             const ushort* __restrict__ Bl,
                                             size_t astr, size_t bstr, int Kd,
                                             f32x4 (&acc)[4][4]) {
    constexpr int NTL = SPLIT ? 4 : 2;
    constexpr int LOADS = SPLIT ? 8 : 4;
    __shared__ ushort lds[2][NTL * 4096];

    const int tid = threadIdx.x;
    const int lane = tid & 63, wave = tid >> 6;
    const int wr = (wave >> 1) * 64, wc = (wave & 1) * 64;
    const int ln = lane & 15, kb = (lane >> 4) * 8;
    const int NT = Kd >> 5;

    auto stage_all = [&](int kt, int slot) {
        const int k0 = kt * 32;
        stage(&lds[slot][0], Ah + k0, astr);
        stage(&lds[slot][4096], Bh + k0, bstr);
        if constexpr (SPLIT) {
            stage(&lds[slot][8192], Al + k0, astr);
            stage(&lds[slot][12288], Bl + k0, bstr);
        }
    };

    stage_all(0, 0);
    stage_all(1, 1);
    asm volatile("s_waitcnt vmcnt(%0)" ::"i"(LOADS) : "memory");
    __builtin_amdgcn_sched_barrier(0);
    __builtin_amdgcn_s_barrier();

    for (int t = 0; t < NT; ++t) {
        __builtin_amdgcn_sched_barrier(0);
        const int cur = t & 1;
        const ushort* sAh = &lds[cur][0];
        const ushort* sBh = &lds[cur][4096];

        bf16x8 bh[4], bl[4];
#pragma unroll
        for (int n = 0; n < 4; ++n) {
            bh[n] = *(const bf16x8*)&sBh[(size_t)(wc + n * 16 + ln) * 32 + kb];
            if constexpr (SPLIT)
                bl[n] = *(const bf16x8*)&lds[cur][12288 + (size_t)(wc + n * 16 + ln) * 32 + kb];
        }
#pragma unroll
        for (int m = 0; m < 4; ++m) {
            bf16x8 ah = *(const bf16x8*)&sAh[(size_t)(wr + m * 16 + ln) * 32 + kb];
            if constexpr (SPLIT) {
                bf16x8 al = *(const bf16x8*)&lds[cur][8192 + (size_t)(wr + m * 16 + ln) * 32 + kb];
#pragma unroll
                for (int n = 0; n < 4; ++n) {
                    acc[m][n] = mfma_bf16(ah, bh[n], acc[m][n]);
                    acc[m][n] = mfma_bf16(ah, bl[n], acc[m][n]);
                    acc[m][n] = mfma_bf16(al, bh[n], acc[m][n]);
                }
            } else {
#pragma unroll
                for (int n = 0; n < 4; ++n) acc[m][n] = mfma_bf16(ah, bh[n], acc[m][n]);
            }
        }

        asm volatile("s_waitcnt lgkmcnt(0)" ::: "memory");
        __builtin_amdgcn_sched_barrier(0);
        __builtin_amdgcn_s_barrier();

        if (t + 2 < NT) {
            stage_all(t + 2, cur);
            asm volatile("s_waitcnt vmcnt(%0)" ::"i"(LOADS) : "memory");
            __builtin_amdgcn_sched_barrier(0);
            __builtin_amdgcn_s_barrier();
        } else if (t + 1 < NT) {
            asm volatile("s_waitcnt vmcnt(0)" ::: "memory");
            __builtin_amdgcn_sched_barrier(0);
            __builtin_amdgcn_s_barrier();
        }
    }
    asm volatile("s_waitcnt vmcnt(0)" ::: "memory");  // drain (short-NT safety)
}

// ---------------------------------------------------------------------------
// Mt = (Wq*Wk^T)^T as the NT B-operand for Y = X*M. fp32, split hi/lo.
// ---------------------------------------------------------------------------
__global__ __launch_bounds__(256) void compute_m(const float* __restrict__ Wq,
                                                 const float* __restrict__ Wk,
                                                 ushort* __restrict__ Mthi,
                                                 ushort* __restrict__ Mtlo) {
    __shared__ float As[16][65], Bs[16][65];
    const int tid = threadIdx.x;
    const int row0 = blockIdx.y * 64;
    const int col0 = blockIdx.x * 64;
    const int tx = tid & 15, ty = tid >> 4;
    const int ar = tid >> 2, ac = (tid & 3) * 4;

    float acc[4][4] = {};
    for (int k0 = 0; k0 < On; k0 += 16) {
        float4 av = *(const float4*)&Wk[(size_t)(row0 + ar) * On + k0 + ac];
        As[ac + 0][ar] = av.x;
        As[ac + 1][ar] = av.y;
        As[ac + 2][ar] = av.z;
        As[ac + 3][ar] = av.w;
        float4 bv = *(const float4*)&Wq[(size_t)(col0 + ar) * On + k0 + ac];
        Bs[ac + 0][ar] = bv.x;
        Bs[ac + 1][ar] = bv.y;
        Bs[ac + 2][ar] = bv.z;
        Bs[ac + 3][ar] = bv.w;
        __syncthreads();
#pragma unroll
        for (int kk = 0; kk < 16; ++kk) {
            float a[4], b[4];
#pragma unroll
            for (int x = 0; x < 4; ++x) {
                a[x] = As[kk][ty * 4 + x];
                b[x] = Bs[kk][tx * 4 + x];
            }
#pragma unroll
            for (int ii = 0; ii < 4; ++ii)
#pragma unroll
                for (int jj = 0; jj < 4; ++jj) acc[ii][jj] = fmaf(a[ii], b[jj], acc[ii][jj]);
        }
        __syncthreads();
    }

#pragma unroll
    for (int ii = 0; ii < 4; ++ii)
#pragma unroll
        for (int jj = 0; jj < 4; ++jj) {
            const int i = row0 + ty * 4 + ii;
            const int j = col0 + tx * 4 + jj;
            const float f = acc[ii][jj];
            const ushort h = f2bf(f);
            Mthi[(size_t)i * En + j] = h;
            Mtlo[(size_t)i * En + j] = f2bf(f - bf2f(h));
        }
}

// ---------------------------------------------------------------------------
// Wv [E,O] fp32 -> wvhi [o][e] bf16 (transposed, hi only).
// ---------------------------------------------------------------------------
__global__ __launch_bounds__(256) void convert_wv(const float* __restrict__ Wv,
                                                  ushort* __restrict__ wvhi) {
    __shared__ float tile[32][33];
    const int n0 = blockIdx.x * 32, k0 = blockIdx.y * 32;
    const int tid = threadIdx.x;
    const int r = tid >> 3, c4 = (tid & 7) * 4;
    float4 wv = *(const float4*)&Wv[(size_t)(k0 + r) * On + n0 + c4];
    tile[r][c4 + 0] = wv.x;
    tile[r][c4 + 1] = wv.y;
    tile[r][c4 + 2] = wv.z;
    tile[r][c4 + 3] = wv.w;
    __syncthreads();
    ushort4 hs;
    ushort* hp = &hs.x;
#pragma unroll
    for (int jj = 0; jj < 4; ++jj) hp[jj] = f2bf(tile[c4 + jj][r]);
    *(ushort4*)&wvhi[(size_t)(n0 + r) * En + k0 + c4] = hs;
}

// ---------------------------------------------------------------------------
// X [32768, 512] fp32 -> Xhi / Xlo [32768, 512] bf16
// ---------------------------------------------------------------------------
__global__ __launch_bounds__(256) void convert_x(const float* __restrict__ X,
                                                 ushort* __restrict__ Xhi,
                                                 ushort* __restrict__ Xlo) {
    const int g = blockIdx.x * 256 + threadIdx.x;
    const int row = g >> 6;
    const int k0 = (g & 63) * 8;
    const float* xp = X + (size_t)row * En + k0;
    float4 x0 = *(const float4*)xp;
    float4 x1 = *(const float4*)(xp + 4);
    float xs[8] = {x0.x, x0.y, x0.z, x0.w, x1.x, x1.y, x1.z, x1.w};
    bf16x8 hi, lo;
#pragma unroll
    for (int j = 0; j < 8; ++j) {
        ushort h = f2bf(xs[j]);
        hi[j] = (short)h;
        lo[j] = (short)f2bf(xs[j] - bf2f(h));
    }
    *(bf16x8*)(Xhi + (size_t)row * En + k0) = hi;
    *(bf16x8*)(Xlo + (size_t)row * En + k0) = lo;
}

// ---------------------------------------------------------------------------
// Pass 1a: Y = X * M (split 3-term, K=512). grid 1024, batch-aligned XCD
// swizzle (b%8 == XCD). Skips fully-masked row panels (Y rows i>=t unused).
// ---------------------------------------------------------------------------
__global__ __launch_bounds__(256) void gemm_y(const ushort* __restrict__ Xhi,
                                              const ushort* __restrict__ Xlo,
                                              const ushort* __restrict__ Mthi,
                                              const ushort* __restrict__ Mtlo,
                                              const int* __restrict__ traj,
                                              ushort* __restrict__ Yhi,
                                              ushort* __restrict__ Ylo) {
    const int n = blockIdx.x;
    const int xcd = n & 7;
    const int c = n >> 3;
    const int b = xcd + 8 * (c >> 5);
    const int rem = c & 31;
    const int rp = rem >> 2;
    const int x = rem & 3;
    if (rp * 128 >= traj[b]) return;  // masked panel: Y never consumed
    const int row0 = b * Ln + rp * 128;
    const int col0 = x * 128;

    f32x4 acc[4][4] = {};
    nt_core_pipe<true>(Xhi + (size_t)row0 * En, Xlo + (size_t)row0 * En,
                       Mthi + (size_t)col0 * En, Mtlo + (size_t)col0 * En, En, En, En, acc);

    const int tid = threadIdx.x;
    const int lane = tid & 63, wave = tid >> 6;
    const int wr = (wave >> 1) * 64, wc = (wave & 1) * 64;
    const int ln = lane & 15;

#pragma unroll
    for (int m = 0; m < 4; ++m)
#pragma unroll
        for (int nn = 0; nn < 4; ++nn)
#pragma unroll
            for (int rr = 0; rr < 4; ++rr) {
                const int gi = row0 + wr + m * 16 + (lane >> 4) * 4 + rr;
                const int gj = col0 + wc + nn * 16 + ln;
                const float v = acc[m][nn][rr];
                const ushort h = f2bf(v);
                const size_t idx = (size_t)gi * En + gj;
                Yhi[idx] = h;
                Ylo[idx] = f2bf(v - bf2f(h));
            }
}

// ---------------------------------------------------------------------------
// Pass 1b: V = X * Wv^T, plain bf16 -> vt[b][o][l]. grid 1024, batch-aligned.
// Skips masked l-panels (pv's truncated K-loop never reads them).
// ---------------------------------------------------------------------------
__global__ __launch_bounds__(256) void gemm_v(const ushort* __restrict__ Xhi,
                                              const ushort* __restrict__ wvhi,
                                              const int* __restrict__ traj,
                                              ushort* __restrict__ vt) {
    const int n = blockIdx.x;
    const int xcd = n & 7;
    const int c = n >> 3;
    const int b = xcd + 8 * (c >> 5);
    const int rem = c & 31;
    const int rp = rem >> 2;
    const int x = rem & 3;
    if (rp * 128 >= traj[b]) return;  // masked V rows: never read by pv
    const int row0 = b * Ln + rp * 128;
    const int col0 = x * 128;

    f32x4 acc[4][4] = {};
    nt_core_pipe<false>(Xhi + (size_t)row0 * En, nullptr, wvhi + (size_t)col0 * En, nullptr, En,
                        En, En, acc);

    const int tid = threadIdx.x;
    const int lane = tid & 63, wave = tid >> 6;
    const int wr = (wave >> 1) * 64, wc = (wave & 1) * 64;
    const int ln = lane & 15;

    const int lbase = rp * 128;
#pragma unroll
    for (int m = 0; m < 4; ++m)
#pragma unroll
        for (int nn = 0; nn < 4; ++nn) {
            const int gj = col0 + wc + nn * 16 + ln;
            const int l0 = lbase + wr + m * 16 + (lane >> 4) * 4;
            ushort4 u;
            u.x = f2bf(acc[m][nn][0]);
            u.y = f2bf(acc[m][nn][1]);
            u.z = f2bf(acc[m][nn][2]);
            u.w = f2bf(acc[m][nn][3]);
            *(ushort4*)(vt + ((size_t)b * On + gj) * Ln + l0) = u;
        }
}

// ---------------------------------------------------------------------------
// Pass 2 (NEW 256^2): S[b] = Y[b]*X[b]^T (split 3-term, K=512) + sum_k delta.
// 512 threads = 8 waves (2M x 4N), wave tile 128x64, BK=32, 128 KB LDS,
// counted-vmcnt dbuf schedule (r6 invariant scaled up). grid 512; b%8 = XCD.
// Skips fully-masked 256-row panels. Unconditional batched delta epilogue.
// ---------------------------------------------------------------------------
__global__ __launch_bounds__(512, 2) void gemm_scores256(
    const ushort* __restrict__ Yhi, const ushort* __restrict__ Ylo,
    const ushort* __restrict__ Xhi, const ushort* __restrict__ Xlo,
    const float* __restrict__ delta, const int* __restrict__ traj,
    float* __restrict__ S) {
    __shared__ ushort lds[2][4][8192];  // [slot][{Ah,Bh,Al,Bl}][256*32] = 128 KB
    const int n = blockIdx.x;
    const int xcd = n & 7;
    const int c = n >> 3;              // [0,64)
    const int b = xcd + 8 * (c >> 4);  // [0,32)
    const int rem = c & 15;
    const int rp = rem >> 2, cp = rem & 3;
    const int row0 = rp * 256, col0 = cp * 256;
    if (row0 >= traj[b]) return;  // whole 256-row panel masked

    const int tid = threadIdx.x;
    const int lane = tid & 63, wave = tid >> 6;
    const int wm = wave >> 2, wn = wave & 3;  // 2 x 4 wave grid
    const int ln = lane & 15, q4 = lane >> 4, kb = q4 * 8;

    const ushort* Ah = Yhi + ((size_t)b * Ln + row0) * En;
    const ushort* Al = Ylo + ((size_t)b * Ln + row0) * En;
    const ushort* Bh = Xhi + ((size_t)b * Ln + col0) * En;
    const ushort* Bl = Xlo + ((size_t)b * Ln + col0) * En;

    auto stage512 = [&](ushort* dst, const ushort* src) {
#pragma unroll
        for (int cc = 0; cc < 2; ++cc) {
            const int ch = tid + cc * 512;  // 1024 chunks of 16B = 256x32 tile
            const ushort* g = src + (size_t)(ch >> 2) * En + (ch & 3) * 8;
            ushort* l = dst + ((size_t)(cc * 512 + (tid >> 6) * 64)) * 8;
            __builtin_amdgcn_global_load_lds(
                (const __attribute__((address_space(1))) unsigned int*)g,
                (__attribute__((address_space(3))) unsigned int*)l, 16, 0, 0);
        }
    };
    auto stage_all = [&](int kt, int slot) {
        const int k0 = kt * 32;
        stage512(lds[slot][0], Ah + k0);
        stage512(lds[slot][1], Bh + k0);
        stage512(lds[slot][2], Al + k0);
        stage512(lds[slot][3], Bl + k0);
    };

    f32x4 acc[8][4] = {};

    stage_all(0, 0);
    stage_all(1, 1);
    asm volatile("s_waitcnt vmcnt(8)" ::: "memory");  // slot0 done; slot1 in flight
    __builtin_amdgcn_sched_barrier(0);
    __builtin_amdgcn_s_barrier();

    for (int ts = 0; ts < 16; ++ts) {
        __builtin_amdgcn_sched_barrier(0);
        const int cur = ts & 1;
        bf16x8 bh[4], bl[4];
#pragma unroll
        for (int nn = 0; nn < 4; ++nn) {
            const size_t bo = (size_t)(wn * 64 + nn * 16 + ln) * 32 + kb;
            bh[nn] = *(const bf16x8*)&lds[cur][1][bo];
            bl[nn] = *(const bf16x8*)&lds[cur][3][bo];
        }
#pragma unroll
        for (int m = 0; m < 8; ++m) {
            const size_t ao = (size_t)(wm * 128 + m * 16 + ln) * 32 + kb;
            bf16x8 ah = *(const bf16x8*)&lds[cur][0][ao];
            bf16x8 al = *(const bf16x8*)&lds[cur][2][ao];
#pragma unroll
            for (int nn = 0; nn < 4; ++nn) {
                acc[m][nn] = mfma_bf16(ah, bh[nn], acc[m][nn]);
                acc[m][nn] = mfma_bf16(ah, bl[nn], acc[m][nn]);
                acc[m][nn] = mfma_bf16(al, bh[nn], acc[m][nn]);
            }
        }
        asm volatile("s_waitcnt lgkmcnt(0)" ::: "memory");
        __builtin_amdgcn_sched_barrier(0);
        __builtin_amdgcn_s_barrier();  // all waves done reading slot cur

        if (ts + 2 < 16) {
            stage_all(ts + 2, cur);  // overwrite freed slot; stays in flight
            asm volatile("s_waitcnt vmcnt(8)" ::: "memory");  // slot (ts+1) ready
            __builtin_amdgcn_sched_barrier(0);
            __builtin_amdgcn_s_barrier();
        } else if (ts + 1 < 16) {
            asm volatile("s_waitcnt vmcnt(0)" ::: "memory");
            __builtin_amdgcn_sched_barrier(0);
            __builtin_amdgcn_s_barrier();
        }
    }
    asm volatile("s_waitcnt vmcnt(0)" ::: "memory");  // drain

    // epilogue: delta add + S store (unconditional, batched)
#pragma unroll
    for (int m = 0; m < 8; ++m)
#pragma unroll
        for (int nn = 0; nn < 4; ++nn)
#pragma unroll
            for (int rr = 0; rr < 4; ++rr) {
                const int gi = row0 + wm * 128 + m * 16 + q4 * 4 + rr;
                const int gj = col0 + wn * 64 + nn * 16 + ln;
                const float4 dv = *(const float4*)(delta + (((size_t)b * Ln + gi) * Ln + gj) * 4);
                S[((size_t)b * Ln + gi) * Ln + gj] =
                    acc[m][nn][rr] + ((dv.x + dv.y) + (dv.z + dv.w));
            }
}

// ---------------------------------------------------------------------------
// Pass 3: full-row softmax (denom over ALL j), post-softmax mask, P bf16
// in place. r11 batch-aligned swizzle. Rows in fully-masked panels
// (i >= ceil128(t)) exit with no store -- pv never reads their P.
// ---------------------------------------------------------------------------
__global__ __launch_bounds__(256) void softmax_kernel(float* __restrict__ S,
                                                      const int* __restrict__ traj) {
    const int n = blockIdx.x;
    const int xcd = n & 7;
    const int idx = n >> 3;
    const int b = xcd + 8 * (idx >> 10);
    const int i = idx & (Ln - 1);
    const int t = traj[b];
    if (i >= ((t + 127) & ~127)) return;  // fully-masked panel: P never read

    float* Srow = S + ((size_t)b * Ln + i) * Ln;
    ushort* Prow = (ushort*)Srow;
    const int tid = threadIdx.x;
    const int j0 = tid * 4;

    if (i >= t) {  // masked row inside boundary panel: pv reads it -> zero P
        ushort4 z = {0, 0, 0, 0};
        *(ushort4*)&Prow[j0] = z;
        return;
    }

    float4 v = *(const float4*)&Srow[j0];
    __shared__ float red[4];

    float m = fmaxf(fmaxf(v.x, v.y), fmaxf(v.z, v.w));
#pragma unroll
    for (int off = 32; off >= 1; off >>= 1) m = fmaxf(m, __shfl_xor(m, off));
    if ((tid & 63) == 0) red[tid >> 6] = m;
    __syncthreads();
    m = fmaxf(fmaxf(red[0], red[1]), fmaxf(red[2], red[3]));
    __syncthreads();

    float e0 = __expf(v.x - m), e1 = __expf(v.y - m), e2 = __expf(v.z - m), e3 = __expf(v.w - m);
    float s = (e0 + e1) + (e2 + e3);
#pragma unroll
    for (int off = 32; off >= 1; off >>= 1) s += __shfl_xor(s, off);
    if ((tid & 63) == 0) red[tid >> 6] = s;
    __syncthreads();
    s = (red[0] + red[1]) + (red[2] + red[3]);
    const float inv = 1.0f / s;

    ushort4 o;
    o.x = (j0 + 0 < t) ? f2bf(e0 * inv) : (ushort)0;
    o.y = (j0 + 1 < t) ? f2bf(e1 * inv) : (ushort)0;
    o.z = (j0 + 2 < t) ? f2bf(e2 * inv) : (ushort)0;
    o.w = (j0 + 3 < t) ? f2bf(e3 * inv) : (ushort)0;
    *(ushort4*)&Prow[j0] = o;
}

// ---------------------------------------------------------------------------
// Pass 4: out[b] = P[b] (bf16, stride 2048) * V[b]. K truncated to
// ceil32(t). r11 mapping (b%8). Fully-masked panels store exact zeros.
// ---------------------------------------------------------------------------
__global__ __launch_bounds__(256) void gemm_pv(const ushort* __restrict__ P,
                                               const ushort* __restrict__ vt,
                                               const int* __restrict__ traj,
                                               float* __restrict__ out) {
    const int n = blockIdx.x;
    const int xcd = n & 7;
    const int c = n >> 3;
    const int b = (c / 32) * 8 + xcd;
    const int xy = c % 32;
    const int col0 = (xy & 3) * 128;
    const int row0 = (xy >> 2) * 128;
    const int t = traj[b];

    const int tid = threadIdx.x;

    if (row0 >= t) {  // whole output panel masked: exact zeros
        const float4 z = make_float4(0.f, 0.f, 0.f, 0.f);
        for (int i = tid; i < 128 * 32; i += 256) {
            const int r = i >> 5, c4 = (i & 31) * 4;
            *(float4*)&out[((size_t)b * Ln + row0 + r) * On + col0 + c4] = z;
        }
        return;
    }

    const int Kd = ((t + 31) >> 5) << 5;  // P[k]=0 for k>=t -> truncate

    f32x4 acc[4][4] = {};
    nt_core_pipe<false>(P + ((size_t)b * Ln + row0) * 2048, nullptr,
                        vt + ((size_t)b * On + col0) * Ln, nullptr, 2048, Ln, Kd, acc);

    const int lane = tid & 63, wave = tid >> 6;
    const int wr = (wave >> 1) * 64, wc = (wave & 1) * 64;
    const int ln = lane & 15;

#pragma unroll
    for (int m = 0; m < 4; ++m)
#pragma unroll
        for (int nn = 0; nn < 4; ++nn)
#pragma unroll
            for (int rr = 0; rr < 4; ++rr) {
                const int gi = row0 + wr + m * 16 + (lane >> 4) * 4 + rr;
                const int gj = col0 + wc + nn * 16 + ln;
                const float val = (gi < t) ? acc[m][nn][rr] : 0.f;
                out[((size_t)b * Ln + gi) * On + gj] = val;
            }
}

extern "C" void kernel_launch(void* const* d_in, const int* in_sizes, int n_in,
                              void* d_out, int out_size, void* d_ws, size_t ws_size,
                              hipStream_t stream) {
    const float* X = (const float*)d_in[0];      // [B, L, E]
    const float* delta = (const float*)d_in[1];  // [B, L, L, 4]
    const float* Wq = (const float*)d_in[2];     // [E, O]
    const float* Wk = (const float*)d_in[3];
    const float* Wv = (const float*)d_in[4];
    const int* traj = (const int*)d_in[5];       // [B]
    float* out = (float*)d_out;

    // ws layout (ushort units unless noted)
    const size_t NE = (size_t)Bn * Ln * On;  // 16.77M elements
    ushort* Mthi = (ushort*)d_ws;            // 512*512
    ushort* Mtlo = Mthi + (size_t)En * En;
    ushort* wvhi = Mtlo + (size_t)En * En;
    ushort* Xhi = wvhi + (size_t)En * En;
    ushort* Xlo = Xhi + NE;
    ushort* Yhi = Xlo + NE;
    ushort* Ylo = Yhi + NE;
    ushort* vt = Ylo + NE;                   // [B][O][L]
    float* S = (float*)(vt + NE);            // [B][L][L] fp32 / P bf16 in place

    compute_m<<<dim3(En / 64, En / 64), 256, 0, stream>>>(Wq, Wk, Mthi, Mtlo);
    convert_wv<<<dim3(On / 32, En / 32), 256, 0, stream>>>(Wv, wvhi);
    convert_x<<<dim3((Bn * Ln * 64) / 256), 256, 0, stream>>>(X, Xhi, Xlo);
    gemm_y<<<dim3(1024), 256, 0, stream>>>(Xhi, Xlo, Mthi, Mtlo, traj, Yhi, Ylo);
    gemm_v<<<dim3(1024), 256, 0, stream>>>(Xhi, wvhi, traj, vt);
    gemm_scores256<<<dim3(512), 512, 0, stream>>>(Yhi, Ylo, Xhi, Xlo, delta, traj, S);
    softmax_kernel<<<dim3(Bn * Ln), 256, 0, stream>>>(S, traj);
    gemm_pv<<<dim3(1024), 256, 0, stream>>>((const ushort*)S, vt, traj, out);
}

// Round 16
// 341.389 us; speedup vs baseline: 1.1771x; 1.1771x over previous
//
#include <hip/hip_runtime.h>
#include <hip/hip_bf16.h>

#define Bn 32
#define Ln 1024
#define En 512
#define On 512

typedef __attribute__((ext_vector_type(8))) short bf16x8;
typedef __attribute__((ext_vector_type(8))) _Float16 f16x8;
typedef __attribute__((ext_vector_type(4))) float f32x4;

__device__ __forceinline__ ushort f2bf(float x) {
    __hip_bfloat16 h = __float2bfloat16(x);
    return *reinterpret_cast<ushort*>(&h);
}
__device__ __forceinline__ ushort f2h(float x) {
    _Float16 h = (_Float16)x;
    return *reinterpret_cast<ushort*>(&h);
}

// MFMA dispatch: bits held in bf16x8; FP16 variant reinterprets as f16x8.
template <bool FP16>
__device__ __forceinline__ f32x4 frag_mfma(bf16x8 a, bf16x8 b, f32x4 c) {
    if constexpr (FP16)
        return __builtin_amdgcn_mfma_f32_16x16x32_f16(*(f16x8*)&a, *(f16x8*)&b, c, 0, 0, 0);
    else
        return __builtin_amdgcn_mfma_f32_16x16x32_bf16(a, b, c, 0, 0, 0);
}

// ---------------------------------------------------------------------------
// Stage a 128x32 16-bit tile into linear LDS [128][32] via global_load_lds.
// 256 threads * 2 issues * 16B = 8KB.
// ---------------------------------------------------------------------------
__device__ __forceinline__ void stage(ushort* dst, const ushort* src, size_t rstride) {
    const int tid = threadIdx.x;
#pragma unroll
    for (int cc = 0; cc < 2; ++cc) {
        const int c = tid + cc * 256;
        const ushort* g = src + (size_t)(c >> 2) * rstride + (c & 3) * 8;
        ushort* l = dst + ((size_t)(tid >> 6) * 64 + cc * 256) * 8;
        __builtin_amdgcn_global_load_lds(
            (const __attribute__((address_space(1))) unsigned int*)g,
            (__attribute__((address_space(3))) unsigned int*)l, 16, 0, 0);
    }
}

// ---------------------------------------------------------------------------
// Pipelined NT GEMM core (r6-proven schedule, plain 2-tile form): 128x128
// tile, BK=32, 256 threads, double-buffered LDS (32KB) + counted vmcnt +
// raw barriers. FP16 selects fp16 MFMA, else bf16.
// ---------------------------------------------------------------------------
template <bool FP16>
__device__ __forceinline__ void nt_core_pipe(const ushort* __restrict__ Ah,
                                             const ushort* __restrict__ Bh,
                                             size_t astr, size_t bstr, int Kd,
                                             f32x4 (&acc)[4][4]) {
    __shared__ ushort lds[2][2 * 4096];

    const int tid = threadIdx.x;
    const int lane = tid & 63, wave = tid >> 6;
    const int wr = (wave >> 1) * 64, wc = (wave & 1) * 64;
    const int ln = lane & 15, kb = (lane >> 4) * 8;
    const int NT = Kd >> 5;

    auto stage_all = [&](int kt, int slot) {
        const int k0 = kt * 32;
        stage(&lds[slot][0], Ah + k0, astr);
        stage(&lds[slot][4096], Bh + k0, bstr);
    };

    stage_all(0, 0);
    stage_all(1, 1);
    asm volatile("s_waitcnt vmcnt(4)" ::: "memory");
    __builtin_amdgcn_sched_barrier(0);
    __builtin_amdgcn_s_barrier();

    for (int t = 0; t < NT; ++t) {
        __builtin_amdgcn_sched_barrier(0);
        const int cur = t & 1;
        const ushort* sAh = &lds[cur][0];
        const ushort* sBh = &lds[cur][4096];

        bf16x8 bh[4];
#pragma unroll
        for (int n = 0; n < 4; ++n)
            bh[n] = *(const bf16x8*)&sBh[(size_t)(wc + n * 16 + ln) * 32 + kb];
#pragma unroll
        for (int m = 0; m < 4; ++m) {
            bf16x8 ah = *(const bf16x8*)&sAh[(size_t)(wr + m * 16 + ln) * 32 + kb];
#pragma unroll
            for (int n = 0; n < 4; ++n) acc[m][n] = frag_mfma<FP16>(ah, bh[n], acc[m][n]);
        }

        asm volatile("s_waitcnt lgkmcnt(0)" ::: "memory");
        __builtin_amdgcn_sched_barrier(0);
        __builtin_amdgcn_s_barrier();

        if (t + 2 < NT) {
            stage_all(t + 2, cur);
            asm volatile("s_waitcnt vmcnt(4)" ::: "memory");
            __builtin_amdgcn_sched_barrier(0);
            __builtin_amdgcn_s_barrier();
        } else if (t + 1 < NT) {
            asm volatile("s_waitcnt vmcnt(0)" ::: "memory");
            __builtin_amdgcn_sched_barrier(0);
            __builtin_amdgcn_s_barrier();
        }
    }
    asm volatile("s_waitcnt vmcnt(0)" ::: "memory");  // drain (short-NT safety)
}

// ---------------------------------------------------------------------------
// Mt = (Wq*Wk^T)^T as the NT B-operand for Y = X*M. fp32 compute, fp16 out.
// ---------------------------------------------------------------------------
__global__ __launch_bounds__(256) void compute_m(const float* __restrict__ Wq,
                                                 const float* __restrict__ Wk,
                                                 ushort* __restrict__ Mt) {
    __shared__ float As[16][65], Bs[16][65];
    const int tid = threadIdx.x;
    const int row0 = blockIdx.y * 64;
    const int col0 = blockIdx.x * 64;
    const int tx = tid & 15, ty = tid >> 4;
    const int ar = tid >> 2, ac = (tid & 3) * 4;

    float acc[4][4] = {};
    for (int k0 = 0; k0 < On; k0 += 16) {
        float4 av = *(const float4*)&Wk[(size_t)(row0 + ar) * On + k0 + ac];
        As[ac + 0][ar] = av.x;
        As[ac + 1][ar] = av.y;
        As[ac + 2][ar] = av.z;
        As[ac + 3][ar] = av.w;
        float4 bv = *(const float4*)&Wq[(size_t)(col0 + ar) * On + k0 + ac];
        Bs[ac + 0][ar] = bv.x;
        Bs[ac + 1][ar] = bv.y;
        Bs[ac + 2][ar] = bv.z;
        Bs[ac + 3][ar] = bv.w;
        __syncthreads();
#pragma unroll
        for (int kk = 0; kk < 16; ++kk) {
            float a[4], b[4];
#pragma unroll
            for (int x = 0; x < 4; ++x) {
                a[x] = As[kk][ty * 4 + x];
                b[x] = Bs[kk][tx * 4 + x];
            }
#pragma unroll
            for (int ii = 0; ii < 4; ++ii)
#pragma unroll
                for (int jj = 0; jj < 4; ++jj) acc[ii][jj] = fmaf(a[ii], b[jj], acc[ii][jj]);
        }
        __syncthreads();
    }

#pragma unroll
    for (int ii = 0; ii < 4; ++ii)
#pragma unroll
        for (int jj = 0; jj < 4; ++jj) {
            const int i = row0 + ty * 4 + ii;
            const int j = col0 + tx * 4 + jj;
            Mt[(size_t)i * En + j] = f2h(acc[ii][jj]);
        }
}

// ---------------------------------------------------------------------------
// Wv [E,O] fp32 -> wv [o][e] fp16 (transposed).
// ---------------------------------------------------------------------------
__global__ __launch_bounds__(256) void convert_wv(const float* __restrict__ Wv,
                                                  ushort* __restrict__ wv) {
    __shared__ float tile[32][33];
    const int n0 = blockIdx.x * 32, k0 = blockIdx.y * 32;
    const int tid = threadIdx.x;
    const int r = tid >> 3, c4 = (tid & 7) * 4;
    float4 w = *(const float4*)&Wv[(size_t)(k0 + r) * On + n0 + c4];
    tile[r][c4 + 0] = w.x;
    tile[r][c4 + 1] = w.y;
    tile[r][c4 + 2] = w.z;
    tile[r][c4 + 3] = w.w;
    __syncthreads();
    ushort4 hs;
    ushort* hp = &hs.x;
#pragma unroll
    for (int jj = 0; jj < 4; ++jj) hp[jj] = f2h(tile[c4 + jj][r]);
    *(ushort4*)&wv[(size_t)(n0 + r) * En + k0 + c4] = hs;
}

// ---------------------------------------------------------------------------
// X [32768, 512] fp32 -> Xf [32768, 512] fp16
// ---------------------------------------------------------------------------
__global__ __launch_bounds__(256) void convert_x(const float* __restrict__ X,
                                                 ushort* __restrict__ Xf) {
    const int g = blockIdx.x * 256 + threadIdx.x;
    const int row = g >> 6;
    const int k0 = (g & 63) * 8;
    const float* xp = X + (size_t)row * En + k0;
    float4 x0 = *(const float4*)xp;
    float4 x1 = *(const float4*)(xp + 4);
    float xs[8] = {x0.x, x0.y, x0.z, x0.w, x1.x, x1.y, x1.z, x1.w};
    bf16x8 h;
#pragma unroll
    for (int j = 0; j < 8; ++j) h[j] = (short)f2h(xs[j]);
    *(bf16x8*)(Xf + (size_t)row * En + k0) = h;
}

// ---------------------------------------------------------------------------
// Pass 1a: Y = X * M (plain fp16, K=512). grid 1024, batch-aligned XCD
// swizzle. Skips fully-masked row panels. Writes Yf fp16.
// ---------------------------------------------------------------------------
__global__ __launch_bounds__(256) void gemm_y(const ushort* __restrict__ Xf,
                                              const ushort* __restrict__ Mt,
                                              const int* __restrict__ traj,
                                              ushort* __restrict__ Yf) {
    const int n = blockIdx.x;
    const int xcd = n & 7;
    const int c = n >> 3;
    const int b = xcd + 8 * (c >> 5);
    const int rem = c & 31;
    const int rp = rem >> 2;
    const int x = rem & 3;
    if (rp * 128 >= traj[b]) return;  // masked panel: Y never consumed
    const int row0 = b * Ln + rp * 128;
    const int col0 = x * 128;

    f32x4 acc[4][4] = {};
    nt_core_pipe<true>(Xf + (size_t)row0 * En, Mt + (size_t)col0 * En, En, En, En, acc);

    const int tid = threadIdx.x;
    const int lane = tid & 63, wave = tid >> 6;
    const int wr = (wave >> 1) * 64, wc = (wave & 1) * 64;
    const int ln = lane & 15;

#pragma unroll
    for (int m = 0; m < 4; ++m)
#pragma unroll
        for (int nn = 0; nn < 4; ++nn)
#pragma unroll
            for (int rr = 0; rr < 4; ++rr) {
                const int gi = row0 + wr + m * 16 + (lane >> 4) * 4 + rr;
                const int gj = col0 + wc + nn * 16 + ln;
                Yf[(size_t)gi * En + gj] = f2h(acc[m][nn][rr]);
            }
}

// ---------------------------------------------------------------------------
// Pass 1b: V = X * Wv^T (plain fp16) -> vt[b][o][l] bf16. grid 1024,
// batch-aligned. Skips masked l-panels.
// ---------------------------------------------------------------------------
__global__ __launch_bounds__(256) void gemm_v(const ushort* __restrict__ Xf,
                                              const ushort* __restrict__ wv,
                                              const int* __restrict__ traj,
                                              ushort* __restrict__ vt) {
    const int n = blockIdx.x;
    const int xcd = n & 7;
    const int c = n >> 3;
    const int b = xcd + 8 * (c >> 5);
    const int rem = c & 31;
    const int rp = rem >> 2;
    const int x = rem & 3;
    if (rp * 128 >= traj[b]) return;  // masked V rows: never read by pv
    const int row0 = b * Ln + rp * 128;
    const int col0 = x * 128;

    f32x4 acc[4][4] = {};
    nt_core_pipe<true>(Xf + (size_t)row0 * En, wv + (size_t)col0 * En, En, En, En, acc);

    const int tid = threadIdx.x;
    const int lane = tid & 63, wave = tid >> 6;
    const int wr = (wave >> 1) * 64, wc = (wave & 1) * 64;
    const int ln = lane & 15;

    const int lbase = rp * 128;
#pragma unroll
    for (int m = 0; m < 4; ++m)
#pragma unroll
        for (int nn = 0; nn < 4; ++nn) {
            const int gj = col0 + wc + nn * 16 + ln;
            const int l0 = lbase + wr + m * 16 + (lane >> 4) * 4;
            ushort4 u;
            u.x = f2bf(acc[m][nn][0]);
            u.y = f2bf(acc[m][nn][1]);
            u.z = f2bf(acc[m][nn][2]);
            u.w = f2bf(acc[m][nn][3]);
            *(ushort4*)(vt + ((size_t)b * On + gj) * Ln + l0) = u;
        }
}

// ---------------------------------------------------------------------------
// Pass 2: S[b] = Y[b]*X[b]^T (plain fp16, K=512) + sum_k delta -> fp32.
// grid 2048; batch b -> XCD b%8. Skips fully-masked row panels.
// Unconditional batched delta epilogue (r13 lesson).
// ---------------------------------------------------------------------------
__global__ __launch_bounds__(256) void gemm_scores(const ushort* __restrict__ Yf,
                                                   const ushort* __restrict__ Xf,
                                                   const float* __restrict__ delta,
                                                   const int* __restrict__ traj,
                                                   float* __restrict__ S) {
    const int n = blockIdx.x;
    const int xcd = n & 7;
    const int c = n >> 3;
    const int b = (c / 64) * 8 + xcd;
    const int xy = c % 64;
    const int col0 = (xy & 7) * 128;
    const int row0 = (xy >> 3) * 128;
    if (row0 >= traj[b]) return;  // whole panel masked

    const size_t abase = ((size_t)b * Ln + row0) * En;
    const size_t bbase = ((size_t)b * Ln + col0) * En;

    f32x4 acc[4][4] = {};
    nt_core_pipe<true>(Yf + abase, Xf + bbase, En, En, En, acc);

    const int tid = threadIdx.x;
    const int lane = tid & 63, wave = tid >> 6;
    const int wr = (wave >> 1) * 64, wc = (wave & 1) * 64;
    const int ln = lane & 15;

#pragma unroll
    for (int m = 0; m < 4; ++m)
#pragma unroll
        for (int nn = 0; nn < 4; ++nn)
#pragma unroll
            for (int rr = 0; rr < 4; ++rr) {
                const int gi = row0 + wr + m * 16 + (lane >> 4) * 4 + rr;
                const int gj = col0 + wc + nn * 16 + ln;
                const float4 dv = *(const float4*)(delta + (((size_t)b * Ln + gi) * Ln + gj) * 4);
                S[((size_t)b * Ln + gi) * Ln + gj] = acc[m][nn][rr] + ((dv.x + dv.y) + (dv.z + dv.w));
            }
}

// ---------------------------------------------------------------------------
// Pass 3: full-row softmax (denom over ALL j), post-softmax mask, P bf16
// in place. Batch-aligned swizzle. Rows in fully-masked panels exit with
// no store (pv never reads their P).
// ---------------------------------------------------------------------------
__global__ __launch_bounds__(256) void softmax_kernel(float* __restrict__ S,
                                                      const int* __restrict__ traj) {
    const int n = blockIdx.x;
    const int xcd = n & 7;
    const int idx = n >> 3;
    const int b = xcd + 8 * (idx >> 10);
    const int i = idx & (Ln - 1);
    const int t = traj[b];
    if (i >= ((t + 127) & ~127)) return;  // fully-masked panel: P never read

    float* Srow = S + ((size_t)b * Ln + i) * Ln;
    ushort* Prow = (ushort*)Srow;
    const int tid = threadIdx.x;
    const int j0 = tid * 4;

    if (i >= t) {  // masked row inside boundary panel: pv reads it -> zero P
        ushort4 z = {0, 0, 0, 0};
        *(ushort4*)&Prow[j0] = z;
        return;
    }

    float4 v = *(const float4*)&Srow[j0];
    __shared__ float red[4];

    float m = fmaxf(fmaxf(v.x, v.y), fmaxf(v.z, v.w));
#pragma unroll
    for (int off = 32; off >= 1; off >>= 1) m = fmaxf(m, __shfl_xor(m, off));
    if ((tid & 63) == 0) red[tid >> 6] = m;
    __syncthreads();
    m = fmaxf(fmaxf(red[0], red[1]), fmaxf(red[2], red[3]));
    __syncthreads();

    float e0 = __expf(v.x - m), e1 = __expf(v.y - m), e2 = __expf(v.z - m), e3 = __expf(v.w - m);
    float s = (e0 + e1) + (e2 + e3);
#pragma unroll
    for (int off = 32; off >= 1; off >>= 1) s += __shfl_xor(s, off);
    if ((tid & 63) == 0) red[tid >> 6] = s;
    __syncthreads();
    s = (red[0] + red[1]) + (red[2] + red[3]);
    const float inv = 1.0f / s;

    ushort4 o;
    o.x = (j0 + 0 < t) ? f2bf(e0 * inv) : (ushort)0;
    o.y = (j0 + 1 < t) ? f2bf(e1 * inv) : (ushort)0;
    o.z = (j0 + 2 < t) ? f2bf(e2 * inv) : (ushort)0;
    o.w = (j0 + 3 < t) ? f2bf(e3 * inv) : (ushort)0;
    *(ushort4*)&Prow[j0] = o;
}

// ---------------------------------------------------------------------------
// Pass 4: out[b] = P[b] (bf16, stride 2048) * V[b] (bf16). K truncated to
// ceil32(t). Fully-masked panels store exact zeros.
// ---------------------------------------------------------------------------
__global__ __launch_bounds__(256) void gemm_pv(const ushort* __restrict__ P,
                                               const ushort* __restrict__ vt,
                                               const int* __restrict__ traj,
                                               float* __restrict__ out) {
    const int n = blockIdx.x;
    const int xcd = n & 7;
    const int c = n >> 3;
    const int b = (c / 32) * 8 + xcd;
    const int xy = c % 32;
    const int col0 = (xy & 3) * 128;
    const int row0 = (xy >> 2) * 128;
    const int t = traj[b];

    const int tid = threadIdx.x;

    if (row0 >= t) {  // whole output panel masked: exact zeros
        const float4 z = make_float4(0.f, 0.f, 0.f, 0.f);
        for (int i = tid; i < 128 * 32; i += 256) {
            const int r = i >> 5, c4 = (i & 31) * 4;
            *(float4*)&out[((size_t)b * Ln + row0 + r) * On + col0 + c4] = z;
        }
        return;
    }

    const int Kd = ((t + 31) >> 5) << 5;  // P[k]=0 for k>=t -> truncate

    f32x4 acc[4][4] = {};
    nt_core_pipe<false>(P + ((size_t)b * Ln + row0) * 2048,
                        vt + ((size_t)b * On + col0) * Ln, 2048, Ln, Kd, acc);

    const int lane = tid & 63, wave = tid >> 6;
    const int wr = (wave >> 1) * 64, wc = (wave & 1) * 64;
    const int ln = lane & 15;

#pragma unroll
    for (int m = 0; m < 4; ++m)
#pragma unroll
        for (int nn = 0; nn < 4; ++nn)
#pragma unroll
            for (int rr = 0; rr < 4; ++rr) {
                const int gi = row0 + wr + m * 16 + (lane >> 4) * 4 + rr;
                const int gj = col0 + wc + nn * 16 + ln;
                const float val = (gi < t) ? acc[m][nn][rr] : 0.f;
                out[((size_t)b * Ln + gi) * On + gj] = val;
            }
}

extern "C" void kernel_launch(void* const* d_in, const int* in_sizes, int n_in,
                              void* d_out, int out_size, void* d_ws, size_t ws_size,
                              hipStream_t stream) {
    const float* X = (const float*)d_in[0];      // [B, L, E]
    const float* delta = (const float*)d_in[1];  // [B, L, L, 4]
    const float* Wq = (const float*)d_in[2];     // [E, O]
    const float* Wk = (const float*)d_in[3];
    const float* Wv = (const float*)d_in[4];
    const int* traj = (const int*)d_in[5];       // [B]
    float* out = (float*)d_out;

    // ws layout (ushort units unless noted)
    const size_t NE = (size_t)Bn * Ln * On;  // 16.77M elements
    ushort* Mt = (ushort*)d_ws;              // En*En fp16
    ushort* wv = Mt + (size_t)En * En;       // En*En fp16
    ushort* Xf = wv + (size_t)En * En;       // NE fp16
    ushort* Yf = Xf + NE;                    // NE fp16
    ushort* vt = Yf + NE;                    // NE bf16 [B][O][L]
    float* S = (float*)(vt + NE);            // [B][L][L] fp32 / P bf16 in place

    compute_m<<<dim3(En / 64, En / 64), 256, 0, stream>>>(Wq, Wk, Mt);
    convert_wv<<<dim3(On / 32, En / 32), 256, 0, stream>>>(Wv, wv);
    convert_x<<<dim3((Bn * Ln * 64) / 256), 256, 0, stream>>>(X, Xf);
    gemm_y<<<dim3(1024), 256, 0, stream>>>(Xf, Mt, traj, Yf);
    gemm_v<<<dim3(1024), 256, 0, stream>>>(Xf, wv, traj, vt);
    gemm_scores<<<dim3(2048), 256, 0, stream>>>(Yf, Xf, delta, traj, S);
    softmax_kernel<<<dim3(Bn * Ln), 256, 0, stream>>>(S, traj);
    gemm_pv<<<dim3(1024), 256, 0, stream>>>((const ushort*)S, vt, traj, out);
}

// Round 17
// 336.464 us; speedup vs baseline: 1.1943x; 1.0146x over previous
//
#include <hip/hip_runtime.h>
#include <hip/hip_bf16.h>

#define Bn 32
#define Ln 1024
#define En 512
#define On 512

typedef __attribute__((ext_vector_type(8))) short bf16x8;
typedef __attribute__((ext_vector_type(8))) _Float16 f16x8;
typedef __attribute__((ext_vector_type(4))) float f32x4;

__device__ __forceinline__ ushort f2bf(float x) {
    __hip_bfloat16 h = __float2bfloat16(x);
    return *reinterpret_cast<ushort*>(&h);
}
__device__ __forceinline__ ushort f2h(float x) {
    _Float16 h = (_Float16)x;
    return *reinterpret_cast<ushort*>(&h);
}

// MFMA dispatch: bits held in bf16x8; FP16 variant reinterprets as f16x8.
template <bool FP16>
__device__ __forceinline__ f32x4 frag_mfma(bf16x8 a, bf16x8 b, f32x4 c) {
    if constexpr (FP16)
        return __builtin_amdgcn_mfma_f32_16x16x32_f16(*(f16x8*)&a, *(f16x8*)&b, c, 0, 0, 0);
    else
        return __builtin_amdgcn_mfma_f32_16x16x32_bf16(a, b, c, 0, 0, 0);
}

// ---------------------------------------------------------------------------
// Stage a 128x32 16-bit tile into linear LDS [128][32] via global_load_lds.
// 256 threads * 2 issues * 16B = 8KB.
// ---------------------------------------------------------------------------
__device__ __forceinline__ void stage(ushort* dst, const ushort* src, size_t rstride) {
    const int tid = threadIdx.x;
#pragma unroll
    for (int cc = 0; cc < 2; ++cc) {
        const int c = tid + cc * 256;
        const ushort* g = src + (size_t)(c >> 2) * rstride + (c & 3) * 8;
        ushort* l = dst + ((size_t)(tid >> 6) * 64 + cc * 256) * 8;
        __builtin_amdgcn_global_load_lds(
            (const __attribute__((address_space(1))) unsigned int*)g,
            (__attribute__((address_space(3))) unsigned int*)l, 16, 0, 0);
    }
}

// ---------------------------------------------------------------------------
// Pipelined NT GEMM core (r6-proven schedule, plain 2-tile form): 128x128
// tile, BK=32, 256 threads, double-buffered LDS (32KB) + counted vmcnt +
// raw barriers. FP16 selects fp16 MFMA, else bf16.
// ---------------------------------------------------------------------------
template <bool FP16>
__device__ __forceinline__ void nt_core_pipe(const ushort* __restrict__ Ah,
                                             const ushort* __restrict__ Bh,
                                             size_t astr, size_t bstr, int Kd,
                                             f32x4 (&acc)[4][4]) {
    __shared__ ushort lds[2][2 * 4096];

    const int tid = threadIdx.x;
    const int lane = tid & 63, wave = tid >> 6;
    const int wr = (wave >> 1) * 64, wc = (wave & 1) * 64;
    const int ln = lane & 15, kb = (lane >> 4) * 8;
    const int NT = Kd >> 5;

    auto stage_all = [&](int kt, int slot) {
        const int k0 = kt * 32;
        stage(&lds[slot][0], Ah + k0, astr);
        stage(&lds[slot][4096], Bh + k0, bstr);
    };

    stage_all(0, 0);
    stage_all(1, 1);
    asm volatile("s_waitcnt vmcnt(4)" ::: "memory");
    __builtin_amdgcn_sched_barrier(0);
    __builtin_amdgcn_s_barrier();

    for (int t = 0; t < NT; ++t) {
        __builtin_amdgcn_sched_barrier(0);
        const int cur = t & 1;
        const ushort* sAh = &lds[cur][0];
        const ushort* sBh = &lds[cur][4096];

        bf16x8 bh[4];
#pragma unroll
        for (int n = 0; n < 4; ++n)
            bh[n] = *(const bf16x8*)&sBh[(size_t)(wc + n * 16 + ln) * 32 + kb];
#pragma unroll
        for (int m = 0; m < 4; ++m) {
            bf16x8 ah = *(const bf16x8*)&sAh[(size_t)(wr + m * 16 + ln) * 32 + kb];
#pragma unroll
            for (int n = 0; n < 4; ++n) acc[m][n] = frag_mfma<FP16>(ah, bh[n], acc[m][n]);
        }

        asm volatile("s_waitcnt lgkmcnt(0)" ::: "memory");
        __builtin_amdgcn_sched_barrier(0);
        __builtin_amdgcn_s_barrier();

        if (t + 2 < NT) {
            stage_all(t + 2, cur);
            asm volatile("s_waitcnt vmcnt(4)" ::: "memory");
            __builtin_amdgcn_sched_barrier(0);
            __builtin_amdgcn_s_barrier();
        } else if (t + 1 < NT) {
            asm volatile("s_waitcnt vmcnt(0)" ::: "memory");
            __builtin_amdgcn_sched_barrier(0);
            __builtin_amdgcn_s_barrier();
        }
    }
    asm volatile("s_waitcnt vmcnt(0)" ::: "memory");  // drain (short-NT safety)
}

// ---------------------------------------------------------------------------
// Mt = (Wq*Wk^T)^T as the NT B-operand for Y = X*M. fp32 compute, fp16 out.
// ---------------------------------------------------------------------------
__global__ __launch_bounds__(256) void compute_m(const float* __restrict__ Wq,
                                                 const float* __restrict__ Wk,
                                                 ushort* __restrict__ Mt) {
    __shared__ float As[16][65], Bs[16][65];
    const int tid = threadIdx.x;
    const int row0 = blockIdx.y * 64;
    const int col0 = blockIdx.x * 64;
    const int tx = tid & 15, ty = tid >> 4;
    const int ar = tid >> 2, ac = (tid & 3) * 4;

    float acc[4][4] = {};
    for (int k0 = 0; k0 < On; k0 += 16) {
        float4 av = *(const float4*)&Wk[(size_t)(row0 + ar) * On + k0 + ac];
        As[ac + 0][ar] = av.x;
        As[ac + 1][ar] = av.y;
        As[ac + 2][ar] = av.z;
        As[ac + 3][ar] = av.w;
        float4 bv = *(const float4*)&Wq[(size_t)(col0 + ar) * On + k0 + ac];
        Bs[ac + 0][ar] = bv.x;
        Bs[ac + 1][ar] = bv.y;
        Bs[ac + 2][ar] = bv.z;
        Bs[ac + 3][ar] = bv.w;
        __syncthreads();
#pragma unroll
        for (int kk = 0; kk < 16; ++kk) {
            float a[4], b[4];
#pragma unroll
            for (int x = 0; x < 4; ++x) {
                a[x] = As[kk][ty * 4 + x];
                b[x] = Bs[kk][tx * 4 + x];
            }
#pragma unroll
            for (int ii = 0; ii < 4; ++ii)
#pragma unroll
                for (int jj = 0; jj < 4; ++jj) acc[ii][jj] = fmaf(a[ii], b[jj], acc[ii][jj]);
        }
        __syncthreads();
    }

#pragma unroll
    for (int ii = 0; ii < 4; ++ii)
#pragma unroll
        for (int jj = 0; jj < 4; ++jj) {
            const int i = row0 + ty * 4 + ii;
            const int j = col0 + tx * 4 + jj;
            Mt[(size_t)i * En + j] = f2h(acc[ii][jj]);
        }
}

// ---------------------------------------------------------------------------
// Wv [E,O] fp32 -> wv [o][e] fp16 (transposed).
// ---------------------------------------------------------------------------
__global__ __launch_bounds__(256) void convert_wv(const float* __restrict__ Wv,
                                                  ushort* __restrict__ wv) {
    __shared__ float tile[32][33];
    const int n0 = blockIdx.x * 32, k0 = blockIdx.y * 32;
    const int tid = threadIdx.x;
    const int r = tid >> 3, c4 = (tid & 7) * 4;
    float4 w = *(const float4*)&Wv[(size_t)(k0 + r) * On + n0 + c4];
    tile[r][c4 + 0] = w.x;
    tile[r][c4 + 1] = w.y;
    tile[r][c4 + 2] = w.z;
    tile[r][c4 + 3] = w.w;
    __syncthreads();
    ushort4 hs;
    ushort* hp = &hs.x;
#pragma unroll
    for (int jj = 0; jj < 4; ++jj) hp[jj] = f2h(tile[c4 + jj][r]);
    *(ushort4*)&wv[(size_t)(n0 + r) * En + k0 + c4] = hs;
}

// ---------------------------------------------------------------------------
// X [32768, 512] fp32 -> Xf [32768, 512] fp16
// ---------------------------------------------------------------------------
__global__ __launch_bounds__(256) void convert_x(const float* __restrict__ X,
                                                 ushort* __restrict__ Xf) {
    const int g = blockIdx.x * 256 + threadIdx.x;
    const int row = g >> 6;
    const int k0 = (g & 63) * 8;
    const float* xp = X + (size_t)row * En + k0;
    float4 x0 = *(const float4*)xp;
    float4 x1 = *(const float4*)(xp + 4);
    float xs[8] = {x0.x, x0.y, x0.z, x0.w, x1.x, x1.y, x1.z, x1.w};
    bf16x8 h;
#pragma unroll
    for (int j = 0; j < 8; ++j) h[j] = (short)f2h(xs[j]);
    *(bf16x8*)(Xf + (size_t)row * En + k0) = h;
}

// ---------------------------------------------------------------------------
// Pass 1 (merged): n<1024: Y = X*M (fp16) -> Yf; n>=1024: V = X*Wv^T (fp16)
// -> vt[b][o][l] bf16. Both paths plain fp16 nt_core_pipe, 32KB LDS.
// Batch-aligned XCD swizzle; skips fully-masked row panels.
// ---------------------------------------------------------------------------
__global__ __launch_bounds__(256) void gemm_yv(const ushort* __restrict__ Xf,
                                               const ushort* __restrict__ Mt,
                                               const ushort* __restrict__ wv,
                                               const int* __restrict__ traj,
                                               ushort* __restrict__ Yf,
                                               ushort* __restrict__ vt) {
    const bool is_y = blockIdx.x < 1024;
    const int n = is_y ? blockIdx.x : (blockIdx.x - 1024);
    const int xcd = n & 7;
    const int c = n >> 3;
    const int b = xcd + 8 * (c >> 5);
    const int rem = c & 31;
    const int rp = rem >> 2;
    const int x = rem & 3;
    if (rp * 128 >= traj[b]) return;  // masked panel: output never consumed
    const int row0 = b * Ln + rp * 128;
    const int col0 = x * 128;

    const ushort* Bop = is_y ? (Mt + (size_t)col0 * En) : (wv + (size_t)col0 * En);

    f32x4 acc[4][4] = {};
    nt_core_pipe<true>(Xf + (size_t)row0 * En, Bop, En, En, En, acc);

    const int tid = threadIdx.x;
    const int lane = tid & 63, wave = tid >> 6;
    const int wr = (wave >> 1) * 64, wc = (wave & 1) * 64;
    const int ln = lane & 15;

    if (is_y) {
#pragma unroll
        for (int m = 0; m < 4; ++m)
#pragma unroll
            for (int nn = 0; nn < 4; ++nn)
#pragma unroll
                for (int rr = 0; rr < 4; ++rr) {
                    const int gi = row0 + wr + m * 16 + (lane >> 4) * 4 + rr;
                    const int gj = col0 + wc + nn * 16 + ln;
                    Yf[(size_t)gi * En + gj] = f2h(acc[m][nn][rr]);
                }
    } else {
        const int lbase = rp * 128;
#pragma unroll
        for (int m = 0; m < 4; ++m)
#pragma unroll
            for (int nn = 0; nn < 4; ++nn) {
                const int gj = col0 + wc + nn * 16 + ln;
                const int l0 = lbase + wr + m * 16 + (lane >> 4) * 4;
                ushort4 u;
                u.x = f2bf(acc[m][nn][0]);
                u.y = f2bf(acc[m][nn][1]);
                u.z = f2bf(acc[m][nn][2]);
                u.w = f2bf(acc[m][nn][3]);
                *(ushort4*)(vt + ((size_t)b * On + gj) * Ln + l0) = u;
            }
    }
}

// ---------------------------------------------------------------------------
// Pass 2: S[b] = Y[b]*X[b]^T (plain fp16, K=512) + sum_k delta -> fp32.
// grid 2048; batch b -> XCD b%8. Skips fully-masked row panels.
// Unconditional batched delta epilogue (r13 lesson).
// ---------------------------------------------------------------------------
__global__ __launch_bounds__(256) void gemm_scores(const ushort* __restrict__ Yf,
                                                   const ushort* __restrict__ Xf,
                                                   const float* __restrict__ delta,
                                                   const int* __restrict__ traj,
                                                   float* __restrict__ S) {
    const int n = blockIdx.x;
    const int xcd = n & 7;
    const int c = n >> 3;
    const int b = (c / 64) * 8 + xcd;
    const int xy = c % 64;
    const int col0 = (xy & 7) * 128;
    const int row0 = (xy >> 3) * 128;
    if (row0 >= traj[b]) return;  // whole panel masked

    const size_t abase = ((size_t)b * Ln + row0) * En;
    const size_t bbase = ((size_t)b * Ln + col0) * En;

    f32x4 acc[4][4] = {};
    nt_core_pipe<true>(Yf + abase, Xf + bbase, En, En, En, acc);

    const int tid = threadIdx.x;
    const int lane = tid & 63, wave = tid >> 6;
    const int wr = (wave >> 1) * 64, wc = (wave & 1) * 64;
    const int ln = lane & 15;

#pragma unroll
    for (int m = 0; m < 4; ++m)
#pragma unroll
        for (int nn = 0; nn < 4; ++nn)
#pragma unroll
            for (int rr = 0; rr < 4; ++rr) {
                const int gi = row0 + wr + m * 16 + (lane >> 4) * 4 + rr;
                const int gj = col0 + wc + nn * 16 + ln;
                const float4 dv = *(const float4*)(delta + (((size_t)b * Ln + gi) * Ln + gj) * 4);
                S[((size_t)b * Ln + gi) * Ln + gj] = acc[m][nn][rr] + ((dv.x + dv.y) + (dv.z + dv.w));
            }
}

// ---------------------------------------------------------------------------
// Pass 3: full-row softmax (denom over ALL j), post-softmax mask, P bf16
// in place. Batch-aligned swizzle. Rows in fully-masked panels exit with
// no store (pv never reads their P).
// ---------------------------------------------------------------------------
__global__ __launch_bounds__(256) void softmax_kernel(float* __restrict__ S,
                                                      const int* __restrict__ traj) {
    const int n = blockIdx.x;
    const int xcd = n & 7;
    const int idx = n >> 3;
    const int b = xcd + 8 * (idx >> 10);
    const int i = idx & (Ln - 1);
    const int t = traj[b];
    if (i >= ((t + 127) & ~127)) return;  // fully-masked panel: P never read

    float* Srow = S + ((size_t)b * Ln + i) * Ln;
    ushort* Prow = (ushort*)Srow;
    const int tid = threadIdx.x;
    const int j0 = tid * 4;

    if (i >= t) {  // masked row inside boundary panel: pv reads it -> zero P
        ushort4 z = {0, 0, 0, 0};
        *(ushort4*)&Prow[j0] = z;
        return;
    }

    float4 v = *(const float4*)&Srow[j0];
    __shared__ float red[4];

    float m = fmaxf(fmaxf(v.x, v.y), fmaxf(v.z, v.w));
#pragma unroll
    for (int off = 32; off >= 1; off >>= 1) m = fmaxf(m, __shfl_xor(m, off));
    if ((tid & 63) == 0) red[tid >> 6] = m;
    __syncthreads();
    m = fmaxf(fmaxf(red[0], red[1]), fmaxf(red[2], red[3]));
    __syncthreads();

    float e0 = __expf(v.x - m), e1 = __expf(v.y - m), e2 = __expf(v.z - m), e3 = __expf(v.w - m);
    float s = (e0 + e1) + (e2 + e3);
#pragma unroll
    for (int off = 32; off >= 1; off >>= 1) s += __shfl_xor(s, off);
    if ((tid & 63) == 0) red[tid >> 6] = s;
    __syncthreads();
    s = (red[0] + red[1]) + (red[2] + red[3]);
    const float inv = 1.0f / s;

    ushort4 o;
    o.x = (j0 + 0 < t) ? f2bf(e0 * inv) : (ushort)0;
    o.y = (j0 + 1 < t) ? f2bf(e1 * inv) : (ushort)0;
    o.z = (j0 + 2 < t) ? f2bf(e2 * inv) : (ushort)0;
    o.w = (j0 + 3 < t) ? f2bf(e3 * inv) : (ushort)0;
    *(ushort4*)&Prow[j0] = o;
}

// ---------------------------------------------------------------------------
// Pass 4: out[b] = P[b] (bf16, stride 2048) * V[b] (bf16). K truncated to
// ceil32(t). Fully-masked panels store exact zeros.
// ---------------------------------------------------------------------------
__global__ __launch_bounds__(256) void gemm_pv(const ushort* __restrict__ P,
                                               const ushort* __restrict__ vt,
                                               const int* __restrict__ traj,
                                               float* __restrict__ out) {
    const int n = blockIdx.x;
    const int xcd = n & 7;
    const int c = n >> 3;
    const int b = (c / 32) * 8 + xcd;
    const int xy = c % 32;
    const int col0 = (xy & 3) * 128;
    const int row0 = (xy >> 2) * 128;
    const int t = traj[b];

    const int tid = threadIdx.x;

    if (row0 >= t) {  // whole output panel masked: exact zeros
        const float4 z = make_float4(0.f, 0.f, 0.f, 0.f);
        for (int i = tid; i < 128 * 32; i += 256) {
            const int r = i >> 5, c4 = (i & 31) * 4;
            *(float4*)&out[((size_t)b * Ln + row0 + r) * On + col0 + c4] = z;
        }
        return;
    }

    const int Kd = ((t + 31) >> 5) << 5;  // P[k]=0 for k>=t -> truncate

    f32x4 acc[4][4] = {};
    nt_core_pipe<false>(P + ((size_t)b * Ln + row0) * 2048,
                        vt + ((size_t)b * On + col0) * Ln, 2048, Ln, Kd, acc);

    const int lane = tid & 63, wave = tid >> 6;
    const int wr = (wave >> 1) * 64, wc = (wave & 1) * 64;
    const int ln = lane & 15;

#pragma unroll
    for (int m = 0; m < 4; ++m)
#pragma unroll
        for (int nn = 0; nn < 4; ++nn)
#pragma unroll
            for (int rr = 0; rr < 4; ++rr) {
                const int gi = row0 + wr + m * 16 + (lane >> 4) * 4 + rr;
                const int gj = col0 + wc + nn * 16 + ln;
                const float val = (gi < t) ? acc[m][nn][rr] : 0.f;
                out[((size_t)b * Ln + gi) * On + gj] = val;
            }
}

extern "C" void kernel_launch(void* const* d_in, const int* in_sizes, int n_in,
                              void* d_out, int out_size, void* d_ws, size_t ws_size,
                              hipStream_t stream) {
    const float* X = (const float*)d_in[0];      // [B, L, E]
    const float* delta = (const float*)d_in[1];  // [B, L, L, 4]
    const float* Wq = (const float*)d_in[2];     // [E, O]
    const float* Wk = (const float*)d_in[3];
    const float* Wv = (const float*)d_in[4];
    const int* traj = (const int*)d_in[5];       // [B]
    float* out = (float*)d_out;

    // ws layout (ushort units unless noted)
    const size_t NE = (size_t)Bn * Ln * On;  // 16.77M elements
    ushort* Mt = (ushort*)d_ws;              // En*En fp16
    ushort* wv = Mt + (size_t)En * En;       // En*En fp16
    ushort* Xf = wv + (size_t)En * En;       // NE fp16
    ushort* Yf = Xf + NE;                    // NE fp16
    ushort* vt = Yf + NE;                    // NE bf16 [B][O][L]
    float* S = (float*)(vt + NE);            // [B][L][L] fp32 / P bf16 in place

    compute_m<<<dim3(En / 64, En / 64), 256, 0, stream>>>(Wq, Wk, Mt);
    convert_wv<<<dim3(On / 32, En / 32), 256, 0, stream>>>(Wv, wv);
    convert_x<<<dim3((Bn * Ln * 64) / 256), 256, 0, stream>>>(X, Xf);
    gemm_yv<<<dim3(2048), 256, 0, stream>>>(Xf, Mt, wv, traj, Yf, vt);
    gemm_scores<<<dim3(2048), 256, 0, stream>>>(Yf, Xf, delta, traj, S);
    softmax_kernel<<<dim3(Bn * Ln), 256, 0, stream>>>(S, traj);
    gemm_pv<<<dim3(1024), 256, 0, stream>>>((const ushort*)S, vt, traj, out);
}